// Round 1
// 13711.516 us; speedup vs baseline: 2.0421x; 2.0421x over previous
//
#include <hip/hip_runtime.h>

// Model dims
#define BB 2
#define TT 2048
#define EE 1024
#define HH 16
#define HDD 64
#define VV 32000
#define LL 4
#define FF 4096
#define BT (BB*TT)   // 4096

#define NEG_INF (-__builtin_inff())

// ---------------- block reduction helpers (256 threads = 4 waves) ----------------
__device__ inline float blockReduceSum256(float v) {
  #pragma unroll
  for (int off = 32; off > 0; off >>= 1) v += __shfl_xor(v, off, 64);
  __shared__ float t[4];
  __syncthreads();
  if ((threadIdx.x & 63) == 0) t[threadIdx.x >> 6] = v;
  __syncthreads();
  return t[0] + t[1] + t[2] + t[3];
}

__device__ inline float blockReduceMax256(float v) {
  #pragma unroll
  for (int off = 32; off > 0; off >>= 1) v = fmaxf(v, __shfl_xor(v, off, 64));
  __shared__ float t[4];
  __syncthreads();
  if ((threadIdx.x & 63) == 0) t[threadIdx.x >> 6] = v;
  __syncthreads();
  return fmaxf(fmaxf(t[0], t[1]), fmaxf(t[2], t[3]));
}

// ---------------- embedding ----------------
__global__ __launch_bounds__(256) void embed_kernel(
    const int* __restrict__ idx, const float* __restrict__ tok,
    const float* __restrict__ pos, float* __restrict__ x) {
  long i = (long)blockIdx.x * 256 + threadIdx.x;  // over BT*EE
  int e = (int)(i % EE);
  long bt = i / EE;
  int t = (int)(bt % TT);
  x[i] = tok[(long)idx[bt] * EE + e] + pos[(long)t * EE + e];
}

// ---------------- layernorm: one block per row of E=1024 ----------------
__global__ __launch_bounds__(256) void layernorm_kernel(
    const float* __restrict__ x, const float* __restrict__ g,
    const float* __restrict__ b, float* __restrict__ out) {
  int row = blockIdx.x;
  const float* xr = x + (long)row * EE;
  float* orow = out + (long)row * EE;
  int tid = threadIdx.x;
  float local[4];
  float s = 0.f;
  #pragma unroll
  for (int i = 0; i < 4; ++i) { local[i] = xr[tid + i * 256]; s += local[i]; }
  s = blockReduceSum256(s);
  float mean = s * (1.0f / EE);
  float vs = 0.f;
  #pragma unroll
  for (int i = 0; i < 4; ++i) { float d = local[i] - mean; vs += d * d; }
  vs = blockReduceSum256(vs);
  float rstd = rsqrtf(vs * (1.0f / EE) + 1e-5f);
  #pragma unroll
  for (int i = 0; i < 4; ++i) {
    int c = tid + i * 256;
    orow[c] = (local[i] - mean) * rstd * g[c] + b[c];
  }
}

// ---------------- generic tiled f32 GEMM ----------------
// C[m,n] = sum_k A[m,k]*B[k,n] (+bias[n]) (+res[m,n]) (relu?)
// batched over blockIdx.z: A += (z/zdiv)*sA, B += (z%zdiv)*sB, C/res += z*sC
// Tiles: 64x64 out, BK=16, 256 threads, 4x4 per thread. Dims must divide.
__global__ __launch_bounds__(256) void gemm_f32(
    const float* __restrict__ A, const float* __restrict__ B,
    const float* __restrict__ bias, const float* __restrict__ res,
    float* __restrict__ C, int M, int N, int K, int relu,
    int zdiv, long sA, long sB, long sC) {
  int z = blockIdx.z;
  A += (long)(z / zdiv) * sA;
  B += (long)(z % zdiv) * sB;
  C += (long)z * sC;
  if (res) res += (long)z * sC;

  __shared__ float As[16][65];
  __shared__ float Bs[16][64];
  int tid = threadIdx.x;
  int tx = tid & 15, ty = tid >> 4;     // tx: n-quad, ty: m-quad
  int m0 = blockIdx.y * 64, n0 = blockIdx.x * 64;
  int nn = tid & 63, kk = tid >> 6;

  float acc[4][4] = {};
  for (int k0 = 0; k0 < K; k0 += 16) {
    #pragma unroll
    for (int i = 0; i < 4; ++i)
      As[tx][i * 16 + ty] = A[(long)(m0 + i * 16 + ty) * K + k0 + tx];
    #pragma unroll
    for (int j = 0; j < 4; ++j)
      Bs[j * 4 + kk][nn] = B[(long)(k0 + j * 4 + kk) * N + n0 + nn];
    __syncthreads();
    #pragma unroll
    for (int k = 0; k < 16; ++k) {
      float ra[4], rb[4];
      #pragma unroll
      for (int i = 0; i < 4; ++i) ra[i] = As[k][ty * 4 + i];
      #pragma unroll
      for (int j = 0; j < 4; ++j) rb[j] = Bs[k][tx * 4 + j];
      #pragma unroll
      for (int i = 0; i < 4; ++i)
        #pragma unroll
        for (int j = 0; j < 4; ++j) acc[i][j] += ra[i] * rb[j];
    }
    __syncthreads();
  }
  #pragma unroll
  for (int i = 0; i < 4; ++i) {
    int m = m0 + ty * 4 + i;
    #pragma unroll
    for (int j = 0; j < 4; ++j) {
      int n = n0 + tx * 4 + j;
      float v = acc[i][j];
      if (bias) v += bias[n];
      if (res) v += res[(long)m * N + n];
      if (relu) v = fmaxf(v, 0.f);
      C[(long)m * N + n] = v;
    }
  }
}

// ---------------- causal flash attention, query-tiled ----------------
// 256 threads handle a 64-query tile of one (b,h). K/V tiles staged once per
// 64 queries; QK^T and PV are register-tiled (4x4 per thread) matmuls.
// Online softmax: rows of a thread's ty-group live in a contiguous 16-lane
// group -> __shfl_xor reductions over offsets 1,2,4,8.
// LDS pad=66 words: transposed column writes are 2-way bank-aliased (free),
// float2 reads stay 8B-aligned. K^T buffer is reused for P^T (saves 17 KB).
__global__ __launch_bounds__(256) void attention_tile_kernel(
    const float* __restrict__ q, const float* __restrict__ k,
    const float* __restrict__ v, float* __restrict__ a) {
  int qt = gridDim.x - 1 - blockIdx.x;  // long blocks first
  int bh = blockIdx.y;                  // b*H + h
  int b = bh >> 4, hh = bh & 15;
  int tid = threadIdx.x;
  int tx = tid & 15, ty = tid >> 4;
  int tx4 = tx * 4, ty4 = ty * 4;

  __shared__ float qsT[64][66];  // [e][r], pre-scaled by HD^-0.5
  __shared__ float kpT[64][66];  // K^T tile [e][c]; reused as P^T [s][r]
  __shared__ float vst[64][66];  // V tile [s][c]

  const float* qb = q + ((long)bh * TT + (long)qt * 64) * HDD;
  const float* kb = k + (long)bh * TT * HDD;
  const float* vb = v + (long)bh * TT * HDD;

  // load Q tile, transposed + pre-scaled
  {
    int rr = tid >> 4, e0 = (tid & 15) * 4;
    #pragma unroll
    for (int p = 0; p < 4; ++p) {
      int r = p * 16 + rr;
      float4 qv = *(const float4*)&qb[(long)r * HDD + e0];
      qsT[e0 + 0][r] = qv.x * 0.125f;
      qsT[e0 + 1][r] = qv.y * 0.125f;
      qsT[e0 + 2][r] = qv.z * 0.125f;
      qsT[e0 + 3][r] = qv.w * 0.125f;
    }
  }

  float o[4][4] = {};
  float mrow[4] = {NEG_INF, NEG_INF, NEG_INF, NEG_INF};
  float lrow[4] = {};

  for (int kt = 0; kt <= qt; ++kt) {
    long s0 = (long)kt * 64;
    __syncthreads();  // prev iter done with kpT (as P) and vst
    {
      int rr = tid >> 4, e0 = (tid & 15) * 4;
      #pragma unroll
      for (int p = 0; p < 4; ++p) {
        int r = p * 16 + rr;
        float4 kv = *(const float4*)&kb[(s0 + r) * HDD + e0];
        float4 vv = *(const float4*)&vb[(s0 + r) * HDD + e0];
        kpT[e0 + 0][r] = kv.x; kpT[e0 + 1][r] = kv.y;
        kpT[e0 + 2][r] = kv.z; kpT[e0 + 3][r] = kv.w;
        *(float2*)&vst[r][e0]     = make_float2(vv.x, vv.y);
        *(float2*)&vst[r][e0 + 2] = make_float2(vv.z, vv.w);
      }
    }
    __syncthreads();

    // S = (Q*scale) K^T  — per-thread 4x4
    float sc[4][4] = {};
    #pragma unroll 4
    for (int e = 0; e < 64; ++e) {
      float2 q01 = *(const float2*)&qsT[e][ty4];
      float2 q23 = *(const float2*)&qsT[e][ty4 + 2];
      float2 k01 = *(const float2*)&kpT[e][tx4];
      float2 k23 = *(const float2*)&kpT[e][tx4 + 2];
      float qa[4] = {q01.x, q01.y, q23.x, q23.y};
      float ka[4] = {k01.x, k01.y, k23.x, k23.y};
      #pragma unroll
      for (int i = 0; i < 4; ++i)
        #pragma unroll
        for (int j = 0; j < 4; ++j) sc[i][j] = fmaf(qa[i], ka[j], sc[i][j]);
    }
    if (kt == qt) {  // causal mask only matters on the diagonal tile
      #pragma unroll
      for (int i = 0; i < 4; ++i)
        #pragma unroll
        for (int j = 0; j < 4; ++j)
          if (tx4 + j > ty4 + i) sc[i][j] = NEG_INF;
    }

    // online softmax, rows ty4+i; reduce across the 16 lanes sharing ty
    float cmax[4], csum[4];
    #pragma unroll
    for (int i = 0; i < 4; ++i)
      cmax[i] = fmaxf(fmaxf(sc[i][0], sc[i][1]), fmaxf(sc[i][2], sc[i][3]));
    #pragma unroll
    for (int off = 1; off < 16; off <<= 1) {
      #pragma unroll
      for (int i = 0; i < 4; ++i)
        cmax[i] = fmaxf(cmax[i], __shfl_xor(cmax[i], off, 64));
    }
    float alpha[4];
    #pragma unroll
    for (int i = 0; i < 4; ++i) {
      float mn = fmaxf(mrow[i], cmax[i]);
      alpha[i] = __expf(mrow[i] - mn);  // first tile: exp(-inf)=0
      mrow[i] = mn;
      csum[i] = 0.f;
    }
    #pragma unroll
    for (int i = 0; i < 4; ++i) {
      #pragma unroll
      for (int j = 0; j < 4; ++j) {
        float p = __expf(sc[i][j] - mrow[i]);  // masked -> 0
        sc[i][j] = p;
        csum[i] += p;
      }
    }
    #pragma unroll
    for (int off = 1; off < 16; off <<= 1) {
      #pragma unroll
      for (int i = 0; i < 4; ++i)
        csum[i] += __shfl_xor(csum[i], off, 64);
    }
    #pragma unroll
    for (int i = 0; i < 4; ++i) {
      lrow[i] = lrow[i] * alpha[i] + csum[i];
      #pragma unroll
      for (int j = 0; j < 4; ++j) o[i][j] *= alpha[i];
    }

    __syncthreads();  // everyone done reading kpT as K
    #pragma unroll
    for (int j = 0; j < 4; ++j) {  // P^T[s][r] = P[r][s]
      *(float2*)&kpT[tx4 + j][ty4]     = make_float2(sc[0][j], sc[1][j]);
      *(float2*)&kpT[tx4 + j][ty4 + 2] = make_float2(sc[2][j], sc[3][j]);
    }
    __syncthreads();

    // O += P V
    #pragma unroll 4
    for (int s = 0; s < 64; ++s) {
      float2 p01 = *(const float2*)&kpT[s][ty4];
      float2 p23 = *(const float2*)&kpT[s][ty4 + 2];
      float2 v01 = *(const float2*)&vst[s][tx4];
      float2 v23 = *(const float2*)&vst[s][tx4 + 2];
      float pa[4] = {p01.x, p01.y, p23.x, p23.y};
      float va[4] = {v01.x, v01.y, v23.x, v23.y};
      #pragma unroll
      for (int i = 0; i < 4; ++i)
        #pragma unroll
        for (int j = 0; j < 4; ++j) o[i][j] = fmaf(pa[i], va[j], o[i][j]);
    }
  }

  // write out: a[b][t][hh*64 + c], rows ty4+i, cols tx4+j (16B aligned)
  #pragma unroll
  for (int i = 0; i < 4; ++i) {
    float inv = 1.0f / lrow[i];
    float4 ov = make_float4(o[i][0] * inv, o[i][1] * inv,
                            o[i][2] * inv, o[i][3] * inv);
    *(float4*)&a[((long)b * TT + (long)qt * 64 + ty4 + i) * EE + hh * HDD + tx4] = ov;
  }
}

// ---------------- loss: per-row log-softmax + target gather ----------------
__global__ __launch_bounds__(256) void loss_row_kernel(
    const float* __restrict__ logits, const int* __restrict__ targets,
    float* __restrict__ row_loss) {
  int r = blockIdx.x;
  const float* lr = logits + (long)r * VV;
  int tid = threadIdx.x;
  float mx = NEG_INF;
  for (int i = tid; i < VV; i += 256) mx = fmaxf(mx, lr[i]);
  mx = blockReduceMax256(mx);
  float se = 0.f;
  for (int i = tid; i < VV; i += 256) se += expf(lr[i] - mx);
  se = blockReduceSum256(se);
  if (tid == 0) row_loss[r] = -(lr[targets[r]] - mx - logf(se));
}

__global__ __launch_bounds__(256) void loss_reduce_kernel(
    const float* __restrict__ row_loss, float* __restrict__ out_loss) {
  int tid = threadIdx.x;
  float s = 0.f;
  for (int i = tid; i < BT; i += 256) s += row_loss[i];
  s = blockReduceSum256(s);
  if (tid == 0) out_loss[0] = s * (1.0f / BT);
}

// ---------------- launch ----------------
extern "C" void kernel_launch(void* const* d_in, const int* in_sizes, int n_in,
                              void* d_out, int out_size, void* d_ws, size_t ws_size,
                              hipStream_t stream) {
  (void)in_sizes; (void)n_in; (void)ws_size;
  const int*   idx     = (const int*)d_in[0];
  const int*   targets = (const int*)d_in[1];
  const float* tok_emb = (const float*)d_in[2];
  const float* pos_emb = (const float*)d_in[3];
  const float* Wq      = (const float*)d_in[4];
  const float* Wk      = (const float*)d_in[5];
  const float* Wv      = (const float*)d_in[6];
  const float* Wproj   = (const float*)d_in[7];
  const float* bproj   = (const float*)d_in[8];
  const float* ln1_g   = (const float*)d_in[9];
  const float* ln1_b   = (const float*)d_in[10];
  const float* ln2_g   = (const float*)d_in[11];
  const float* ln2_b   = (const float*)d_in[12];
  const float* W1      = (const float*)d_in[13];
  const float* b1      = (const float*)d_in[14];
  const float* W2      = (const float*)d_in[15];
  const float* b2      = (const float*)d_in[16];
  const float* lnf_g   = (const float*)d_in[17];
  const float* lnf_b   = (const float*)d_in[18];
  const float* Whead   = (const float*)d_in[19];
  const float* bhead   = (const float*)d_in[20];
  float* out = (float*)d_out;

  // workspace layout (floats)
  float* ws = (float*)d_ws;
  float* x    = ws;                 // [BT,E]      4,194,304
  float* hbuf = ws + 4194304;       // [BT,E]
  float* qb   = ws + 8388608;       // [B,H,T,HD]
  float* kb   = ws + 12582912;
  float* vb   = ws + 16777216;
  float* ab   = ws + 20971520;      // [BT,E]
  float* fb   = ws + 25165824;      // [BT,4E]    16,777,216
  float* row_loss = ws + 41943040;  // [BT]

  embed_kernel<<<BT * EE / 256, 256, 0, stream>>>(idx, tok_emb, pos_emb, x);

  for (int l = 0; l < LL; ++l) {
    layernorm_kernel<<<BT, 256, 0, stream>>>(x, ln1_g + l * EE, ln1_b + l * EE, hbuf);
    // QKV: per (b,h) GEMM  [T,E] @ [E,HD] -> [T,HD]
    dim3 gqkv(1, TT / 64, BB * HH);
    long wl = (long)l * HH * EE * HDD;
    gemm_f32<<<gqkv, 256, 0, stream>>>(hbuf, Wq + wl, nullptr, nullptr, qb,
                                       TT, HDD, EE, 0, HH, (long)TT * EE, (long)EE * HDD, (long)TT * HDD);
    gemm_f32<<<gqkv, 256, 0, stream>>>(hbuf, Wk + wl, nullptr, nullptr, kb,
                                       TT, HDD, EE, 0, HH, (long)TT * EE, (long)EE * HDD, (long)TT * HDD);
    gemm_f32<<<gqkv, 256, 0, stream>>>(hbuf, Wv + wl, nullptr, nullptr, vb,
                                       TT, HDD, EE, 0, HH, (long)TT * EE, (long)EE * HDD, (long)TT * HDD);
    attention_tile_kernel<<<dim3(TT / 64, BB * HH), 256, 0, stream>>>(qb, kb, vb, ab);
    // proj + bias + residual (in-place on x)
    gemm_f32<<<dim3(EE / 64, BT / 64, 1), 256, 0, stream>>>(
        ab, Wproj + (long)l * EE * EE, bproj + l * EE, x, x, BT, EE, EE, 0, 1, 0, 0, 0);
    layernorm_kernel<<<BT, 256, 0, stream>>>(x, ln2_g + l * EE, ln2_b + l * EE, hbuf);
    // MLP
    gemm_f32<<<dim3(FF / 64, BT / 64, 1), 256, 0, stream>>>(
        hbuf, W1 + (long)l * EE * FF, b1 + l * FF, nullptr, fb, BT, FF, EE, 1, 1, 0, 0, 0);
    gemm_f32<<<dim3(EE / 64, BT / 64, 1), 256, 0, stream>>>(
        fb, W2 + (long)l * FF * EE, b2 + l * EE, x, x, BT, EE, FF, 0, 1, 0, 0, 0);
  }

  layernorm_kernel<<<BT, 256, 0, stream>>>(x, lnf_g, lnf_b, hbuf);
  // head: logits -> d_out
  gemm_f32<<<dim3(VV / 64, BT / 64, 1), 256, 0, stream>>>(
      hbuf, Whead, bhead, nullptr, out, BT, VV, EE, 0, 1, 0, 0, 0);

  loss_row_kernel<<<BT, 256, 0, stream>>>(out, targets, row_loss);
  loss_reduce_kernel<<<1, 256, 0, stream>>>(row_loss, out + (long)out_size - 1);
}

// Round 2
// 6953.796 us; speedup vs baseline: 4.0267x; 1.9718x over previous
//
#include <hip/hip_runtime.h>

// Model dims
#define BB 2
#define TT 2048
#define EE 1024
#define HH 16
#define HDD 64
#define VV 32000
#define LL 4
#define FF 4096
#define BT (BB*TT)   // 4096

#define NEG_INF (-__builtin_inff())

typedef _Float16 f16;
typedef f16 f16x8 __attribute__((ext_vector_type(8)));
typedef f16 f16x4v __attribute__((ext_vector_type(4)));
typedef float f32x4 __attribute__((ext_vector_type(4)));

// ---------------- block reduction helpers (256 threads = 4 waves) ----------------
__device__ inline float blockReduceSum256(float v) {
  #pragma unroll
  for (int off = 32; off > 0; off >>= 1) v += __shfl_xor(v, off, 64);
  __shared__ float t[4];
  __syncthreads();
  if ((threadIdx.x & 63) == 0) t[threadIdx.x >> 6] = v;
  __syncthreads();
  return t[0] + t[1] + t[2] + t[3];
}

__device__ inline float blockReduceMax256(float v) {
  #pragma unroll
  for (int off = 32; off > 0; off >>= 1) v = fmaxf(v, __shfl_xor(v, off, 64));
  __shared__ float t[4];
  __syncthreads();
  if ((threadIdx.x & 63) == 0) t[threadIdx.x >> 6] = v;
  __syncthreads();
  return fmaxf(fmaxf(t[0], t[1]), fmaxf(t[2], t[3]));
}

// ---------------- embedding ----------------
__global__ __launch_bounds__(256) void embed_kernel(
    const int* __restrict__ idx, const float* __restrict__ tok,
    const float* __restrict__ pos, float* __restrict__ x) {
  long i = (long)blockIdx.x * 256 + threadIdx.x;  // over BT*EE
  int e = (int)(i % EE);
  long bt = i / EE;
  int t = (int)(bt % TT);
  x[i] = tok[(long)idx[bt] * EE + e] + pos[(long)t * EE + e];
}

// ---------------- layernorm: writes f16 hi/lo (consumers are all GEMM-A) ----------------
__global__ __launch_bounds__(256) void layernorm_kernel(
    const float* __restrict__ x, const float* __restrict__ g,
    const float* __restrict__ b, f16* __restrict__ oh, f16* __restrict__ ol) {
  int row = blockIdx.x;
  const float* xr = x + (long)row * EE;
  int tid = threadIdx.x;
  float local[4];
  float s = 0.f;
  #pragma unroll
  for (int i = 0; i < 4; ++i) { local[i] = xr[tid + i * 256]; s += local[i]; }
  s = blockReduceSum256(s);
  float mean = s * (1.0f / EE);
  float vs = 0.f;
  #pragma unroll
  for (int i = 0; i < 4; ++i) { float d = local[i] - mean; vs += d * d; }
  vs = blockReduceSum256(vs);
  float rstd = rsqrtf(vs * (1.0f / EE) + 1e-5f);
  #pragma unroll
  for (int i = 0; i < 4; ++i) {
    int c = tid + i * 256;
    float v = (local[i] - mean) * rstd * g[c] + b[c];
    f16 h = (f16)v;
    oh[(long)row * EE + c] = h;
    ol[(long)row * EE + c] = (f16)(v - (float)h);
  }
}

// ---------------- transpose + f32 -> f16 hi/lo split ----------------
// in: [R][ldIn-strided] f32 (32x32 tile at r0,c0); out: oh/ol [Cext][R] f16.
__global__ __launch_bounds__(256) void transpose_split(
    const float* __restrict__ in, f16* __restrict__ oh, f16* __restrict__ ol,
    int ldIn, int R, long sIn, long sOut) {
  int z = blockIdx.z;
  in += (long)z * sIn; oh += (long)z * sOut; ol += (long)z * sOut;
  __shared__ float t[32][33];
  int r0 = blockIdx.y * 32, c0 = blockIdx.x * 32;
  int tid = threadIdx.x;
  int rr = tid >> 3, cc = (tid & 7) * 4;
  float4 v = *(const float4*)&in[(long)(r0 + rr) * ldIn + c0 + cc];
  t[rr][cc] = v.x; t[rr][cc + 1] = v.y; t[rr][cc + 2] = v.z; t[rr][cc + 3] = v.w;
  __syncthreads();
  int c = tid >> 3, rb = (tid & 7) * 4;
  f16x4v hv, lv;
  #pragma unroll
  for (int j = 0; j < 4; ++j) {
    float xv = t[rb + j][c];
    f16 h = (f16)xv;
    hv[j] = h; lv[j] = (f16)(xv - (float)h);
  }
  long o = (long)(c0 + c) * R + r0 + rb;
  *(f16x4v*)&oh[o] = hv;
  *(f16x4v*)&ol[o] = lv;
}

// ---------------- split-f16 MFMA GEMM ----------------
// C[m,n] = sum_k A[m,k]*B[k,n] with A = Ah+Al (f16 pair, [M][K]),
// B = Bh+Bl stored TRANSPOSED ([N][K]). 3-product split: AhBh + AhBl + AlBh.
// 128x128 tile, BK=32, 4 waves each owning a 64x64 quadrant of 16x16x32 MFMAs.
// Staging via global_load_lds width=16: per-lane global addresses are chosen so
// the LINEAR lds destination (base + lane*16B) IS the MFMA fragment layout:
// block blk=(tid, tid+256) -> row mloc=((blk>>6)<<4)|(blk&15), kgroup (blk>>4)&3.
// Fragment read: lane l of subtile s at block s*64 + (l>>4)*16 + (l&15)  ==
// A[row = s*16+(l&15)][k = (l>>4)*8 + 0..7]  (the 16x16x32 A/B operand layout).
__global__ __launch_bounds__(256, 3) void gemm_mfma(
    const f16* __restrict__ Ah, const f16* __restrict__ Al,
    const f16* __restrict__ Bh, const f16* __restrict__ Bl,
    const float* __restrict__ bias, const float* __restrict__ res,
    float* __restrict__ C, f16* __restrict__ Ch, f16* __restrict__ Cl,
    int ldC, int K, int relu) {
  __shared__ f16 sm[16384];  // halves: Ah[0,4096) Al[4096) Bh[8192) Bl[12288)
  int tid = threadIdx.x;
  int m0 = blockIdx.y << 7, n0 = blockIdx.x << 7;
  int mloc = ((tid >> 6) << 4) | (tid & 15);
  int kg8 = ((tid >> 4) & 3) << 3;
  long offA = (long)(m0 + mloc) * K + kg8;
  long offB = (long)(n0 + mloc) * K + kg8;
  long off64 = 64L * K;
  int lane = tid & 63;
  int w = tid >> 6, wm = w >> 1, wn = w & 1;

  f32x4 acc[4][4] = {};
  for (int ks = 0; ks < K; ks += 32) {
    #define GLL16(g, l) __builtin_amdgcn_global_load_lds( \
        (const __attribute__((address_space(1))) void*)(g), \
        (__attribute__((address_space(3))) void*)(l), 16, 0, 0)
    GLL16(Ah + offA + ks,         &sm[tid * 8]);
    GLL16(Ah + offA + off64 + ks, &sm[2048 + tid * 8]);
    GLL16(Al + offA + ks,         &sm[4096 + tid * 8]);
    GLL16(Al + offA + off64 + ks, &sm[6144 + tid * 8]);
    GLL16(Bh + offB + ks,         &sm[8192 + tid * 8]);
    GLL16(Bh + offB + off64 + ks, &sm[10240 + tid * 8]);
    GLL16(Bl + offB + ks,         &sm[12288 + tid * 8]);
    GLL16(Bl + offB + off64 + ks, &sm[14336 + tid * 8]);
    __syncthreads();   // compiler drains vmcnt before s_barrier

    f16x8 ahf[4], alf[4];
    #pragma unroll
    for (int mi = 0; mi < 4; ++mi) {
      int s = wm * 4 + mi;
      ahf[mi] = *(const f16x8*)&sm[(s * 64 + lane) * 8];
      alf[mi] = *(const f16x8*)&sm[4096 + (s * 64 + lane) * 8];
    }
    #pragma unroll
    for (int ni = 0; ni < 4; ++ni) {
      int s = wn * 4 + ni;
      f16x8 bhf = *(const f16x8*)&sm[8192 + (s * 64 + lane) * 8];
      f16x8 blf = *(const f16x8*)&sm[12288 + (s * 64 + lane) * 8];
      #pragma unroll
      for (int mi = 0; mi < 4; ++mi) {
        acc[mi][ni] = __builtin_amdgcn_mfma_f32_16x16x32_f16(ahf[mi], bhf, acc[mi][ni], 0, 0, 0);
        acc[mi][ni] = __builtin_amdgcn_mfma_f32_16x16x32_f16(ahf[mi], blf, acc[mi][ni], 0, 0, 0);
        acc[mi][ni] = __builtin_amdgcn_mfma_f32_16x16x32_f16(alf[mi], bhf, acc[mi][ni], 0, 0, 0);
      }
    }
    __syncthreads();
  }

  // epilogue: lane l, reg r -> row (l>>4)*4+r, col l&15 of each 16x16 fragment
  int r0 = m0 + wm * 64 + ((lane >> 4) << 2);
  int c0 = n0 + wn * 64 + (lane & 15);
  #pragma unroll
  for (int ni = 0; ni < 4; ++ni) {
    int cn = c0 + ni * 16;
    float bv = bias ? bias[cn] : 0.f;
    #pragma unroll
    for (int mi = 0; mi < 4; ++mi) {
      int rm = r0 + mi * 16;
      #pragma unroll
      for (int r = 0; r < 4; ++r) {
        float v = acc[mi][ni][r] + bv;
        long o = (long)(rm + r) * ldC + cn;
        if (res) v += res[o];
        if (relu) v = fmaxf(v, 0.f);
        if (C) C[o] = v;
        else { f16 h = (f16)v; Ch[o] = h; Cl[o] = (f16)(v - (float)h); }
      }
    }
  }
}

// ---------------- causal flash attention, query-tiled (qkv fused layout) ----------------
// qkv: [B][T][3072] f32 (q | k | v, each [H][64]); out ab_h/ab_l: [BT][E] f16.
__global__ __launch_bounds__(256) void attention_tile_kernel(
    const float* __restrict__ qkv, f16* __restrict__ abh, f16* __restrict__ abl) {
  int qt = gridDim.x - 1 - blockIdx.x;  // long blocks first
  int bh = blockIdx.y;
  int b = bh >> 4, hh = bh & 15;
  int tid = threadIdx.x;
  int tx = tid & 15, ty = tid >> 4;
  int tx4 = tx * 4, ty4 = ty * 4;

  __shared__ float qsT[64][66];  // [e][r], pre-scaled
  __shared__ float kpT[64][66];  // K^T tile [e][c]; reused as P^T [s][r]
  __shared__ float vst[64][66];  // V tile [s][c]

  const float* qb = qkv + ((long)b * TT + (long)qt * 64) * 3072 + hh * 64;
  const float* kb = qkv + (long)b * TT * 3072 + 1024 + hh * 64;
  const float* vb = qkv + (long)b * TT * 3072 + 2048 + hh * 64;

  {
    int rr = tid >> 4, e0 = (tid & 15) * 4;
    #pragma unroll
    for (int p = 0; p < 4; ++p) {
      int r = p * 16 + rr;
      float4 qv = *(const float4*)&qb[(long)r * 3072 + e0];
      qsT[e0 + 0][r] = qv.x * 0.125f;
      qsT[e0 + 1][r] = qv.y * 0.125f;
      qsT[e0 + 2][r] = qv.z * 0.125f;
      qsT[e0 + 3][r] = qv.w * 0.125f;
    }
  }

  float o[4][4] = {};
  float mrow[4] = {NEG_INF, NEG_INF, NEG_INF, NEG_INF};
  float lrow[4] = {};

  for (int kt = 0; kt <= qt; ++kt) {
    long s0 = (long)kt * 64;
    __syncthreads();
    {
      int rr = tid >> 4, e0 = (tid & 15) * 4;
      #pragma unroll
      for (int p = 0; p < 4; ++p) {
        int r = p * 16 + rr;
        float4 kv = *(const float4*)&kb[(s0 + r) * 3072 + e0];
        float4 vv = *(const float4*)&vb[(s0 + r) * 3072 + e0];
        kpT[e0 + 0][r] = kv.x; kpT[e0 + 1][r] = kv.y;
        kpT[e0 + 2][r] = kv.z; kpT[e0 + 3][r] = kv.w;
        *(float2*)&vst[r][e0]     = make_float2(vv.x, vv.y);
        *(float2*)&vst[r][e0 + 2] = make_float2(vv.z, vv.w);
      }
    }
    __syncthreads();

    float sc[4][4] = {};
    #pragma unroll 4
    for (int e = 0; e < 64; ++e) {
      float2 q01 = *(const float2*)&qsT[e][ty4];
      float2 q23 = *(const float2*)&qsT[e][ty4 + 2];
      float2 k01 = *(const float2*)&kpT[e][tx4];
      float2 k23 = *(const float2*)&kpT[e][tx4 + 2];
      float qa[4] = {q01.x, q01.y, q23.x, q23.y};
      float ka[4] = {k01.x, k01.y, k23.x, k23.y};
      #pragma unroll
      for (int i = 0; i < 4; ++i)
        #pragma unroll
        for (int j = 0; j < 4; ++j) sc[i][j] = fmaf(qa[i], ka[j], sc[i][j]);
    }
    if (kt == qt) {
      #pragma unroll
      for (int i = 0; i < 4; ++i)
        #pragma unroll
        for (int j = 0; j < 4; ++j)
          if (tx4 + j > ty4 + i) sc[i][j] = NEG_INF;
    }

    float cmax[4], csum[4];
    #pragma unroll
    for (int i = 0; i < 4; ++i)
      cmax[i] = fmaxf(fmaxf(sc[i][0], sc[i][1]), fmaxf(sc[i][2], sc[i][3]));
    #pragma unroll
    for (int off = 1; off < 16; off <<= 1) {
      #pragma unroll
      for (int i = 0; i < 4; ++i)
        cmax[i] = fmaxf(cmax[i], __shfl_xor(cmax[i], off, 64));
    }
    float alpha[4];
    #pragma unroll
    for (int i = 0; i < 4; ++i) {
      float mn = fmaxf(mrow[i], cmax[i]);
      alpha[i] = __expf(mrow[i] - mn);
      mrow[i] = mn;
      csum[i] = 0.f;
    }
    #pragma unroll
    for (int i = 0; i < 4; ++i) {
      #pragma unroll
      for (int j = 0; j < 4; ++j) {
        float p = __expf(sc[i][j] - mrow[i]);
        sc[i][j] = p;
        csum[i] += p;
      }
    }
    #pragma unroll
    for (int off = 1; off < 16; off <<= 1) {
      #pragma unroll
      for (int i = 0; i < 4; ++i)
        csum[i] += __shfl_xor(csum[i], off, 64);
    }
    #pragma unroll
    for (int i = 0; i < 4; ++i) {
      lrow[i] = lrow[i] * alpha[i] + csum[i];
      #pragma unroll
      for (int j = 0; j < 4; ++j) o[i][j] *= alpha[i];
    }

    __syncthreads();
    #pragma unroll
    for (int j = 0; j < 4; ++j) {
      *(float2*)&kpT[tx4 + j][ty4]     = make_float2(sc[0][j], sc[1][j]);
      *(float2*)&kpT[tx4 + j][ty4 + 2] = make_float2(sc[2][j], sc[3][j]);
    }
    __syncthreads();

    #pragma unroll 4
    for (int s = 0; s < 64; ++s) {
      float2 p01 = *(const float2*)&kpT[s][ty4];
      float2 p23 = *(const float2*)&kpT[s][ty4 + 2];
      float2 v01 = *(const float2*)&vst[s][tx4];
      float2 v23 = *(const float2*)&vst[s][tx4 + 2];
      float pa[4] = {p01.x, p01.y, p23.x, p23.y};
      float va[4] = {v01.x, v01.y, v23.x, v23.y};
      #pragma unroll
      for (int i = 0; i < 4; ++i)
        #pragma unroll
        for (int j = 0; j < 4; ++j) o[i][j] = fmaf(pa[i], va[j], o[i][j]);
    }
  }

  #pragma unroll
  for (int i = 0; i < 4; ++i) {
    float inv = 1.0f / lrow[i];
    long obase = ((long)b * TT + (long)qt * 64 + ty4 + i) * EE + hh * 64 + tx4;
    f16x4v hv, lv;
    #pragma unroll
    for (int j = 0; j < 4; ++j) {
      float vv = o[i][j] * inv;
      f16 h = (f16)vv;
      hv[j] = h; lv[j] = (f16)(vv - (float)h);
    }
    *(f16x4v*)&abh[obase] = hv;
    *(f16x4v*)&abl[obase] = lv;
  }
}

// ---------------- loss ----------------
__global__ __launch_bounds__(256) void loss_row_kernel(
    const float* __restrict__ logits, const int* __restrict__ targets,
    float* __restrict__ row_loss) {
  int r = blockIdx.x;
  const float* lr = logits + (long)r * VV;
  int tid = threadIdx.x;
  float mx = NEG_INF;
  for (int i = tid; i < VV; i += 256) mx = fmaxf(mx, lr[i]);
  mx = blockReduceMax256(mx);
  float se = 0.f;
  for (int i = tid; i < VV; i += 256) se += expf(lr[i] - mx);
  se = blockReduceSum256(se);
  if (tid == 0) row_loss[r] = -(lr[targets[r]] - mx - logf(se));
}

__global__ __launch_bounds__(256) void loss_reduce_kernel(
    const float* __restrict__ row_loss, float* __restrict__ out_loss) {
  int tid = threadIdx.x;
  float s = 0.f;
  for (int i = tid; i < BT; i += 256) s += row_loss[i];
  s = blockReduceSum256(s);
  if (tid == 0) out_loss[0] = s * (1.0f / BT);
}

// ---------------- launch ----------------
extern "C" void kernel_launch(void* const* d_in, const int* in_sizes, int n_in,
                              void* d_out, int out_size, void* d_ws, size_t ws_size,
                              hipStream_t stream) {
  (void)in_sizes; (void)n_in; (void)ws_size;
  const int*   idx     = (const int*)d_in[0];
  const int*   targets = (const int*)d_in[1];
  const float* tok_emb = (const float*)d_in[2];
  const float* pos_emb = (const float*)d_in[3];
  const float* Wq      = (const float*)d_in[4];
  const float* Wk      = (const float*)d_in[5];
  const float* Wv      = (const float*)d_in[6];
  const float* Wproj   = (const float*)d_in[7];
  const float* bproj   = (const float*)d_in[8];
  const float* ln1_g   = (const float*)d_in[9];
  const float* ln1_b   = (const float*)d_in[10];
  const float* ln2_g   = (const float*)d_in[11];
  const float* ln2_b   = (const float*)d_in[12];
  const float* W1      = (const float*)d_in[13];
  const float* b1      = (const float*)d_in[14];
  const float* W2      = (const float*)d_in[15];
  const float* b2      = (const float*)d_in[16];
  const float* lnf_g   = (const float*)d_in[17];
  const float* lnf_b   = (const float*)d_in[18];
  const float* Whead   = (const float*)d_in[19];
  const float* bhead   = (const float*)d_in[20];
  float* out = (float*)d_out;

  // ---- ws layout (bytes); total 149,438,464 B < previous-proven 160 MB ----
  char* W = (char*)d_ws;
  float* x      = (float*)(W + 0);            // [BT][E] f32      16,777,216
  f16* hbuf_h   = (f16*)(W + 16777216);       // [BT][E]           8,388,608
  f16* hbuf_l   = (f16*)(W + 25165824);
  f16* wqkv_h   = (f16*)(W + 33554432);       // [3072][1024]      6,291,456
  f16* wqkv_l   = (f16*)(W + 39845888);
  f16* wp_h     = (f16*)(W + 46137344);       // [1024][1024]      2,097,152
  f16* wp_l     = (f16*)(W + 48234496);
  f16* w1t_h    = (f16*)(W + 50331648);       // [4096][1024]      8,388,608
  f16* w1t_l    = (f16*)(W + 58720256);
  f16* w2t_h    = (f16*)(W + 67108864);       // [1024][4096]      8,388,608
  f16* w2t_l    = (f16*)(W + 75497472);
  f16* wh_h     = (f16*)(W + 83886080);       // [16000][1024]    32,768,000
  f16* wh_l     = (f16*)(W + 116654080);
  float* row_loss = (float*)(W + 149422080);  // [BT]

  // ---- scratch inside d_out (dead before head GEMM writes logits) ----
  char* O = (char*)d_out;
  float* qkvb = (float*)(O + 0);              // [BT][3072] f32   50,331,648
  f16* ab_h   = (f16*)(O + 50331648);         // [BT][E]           8,388,608
  f16* ab_l   = (f16*)(O + 58720256);
  f16* fb_h   = (f16*)(O + 67108864);         // [BT][4E]         33,554,432
  f16* fb_l   = (f16*)(O + 100663296);        // ends 134,217,728 << 524 MB

  embed_kernel<<<BT * EE / 256, 256, 0, stream>>>(idx, tok_emb, pos_emb, x);

  for (int l = 0; l < LL; ++l) {
    layernorm_kernel<<<BT, 256, 0, stream>>>(x, ln1_g + l * EE, ln1_b + l * EE, hbuf_h, hbuf_l);
    // weight converts (transposed [N][K], hi/lo) into per-layer scratch
    transpose_split<<<dim3(2, 32, 16), 256, 0, stream>>>(
        Wq + (long)l * 16 * 65536, wqkv_h,           wqkv_l,           64, 1024, 65536, 65536);
    transpose_split<<<dim3(2, 32, 16), 256, 0, stream>>>(
        Wk + (long)l * 16 * 65536, wqkv_h + 1048576, wqkv_l + 1048576, 64, 1024, 65536, 65536);
    transpose_split<<<dim3(2, 32, 16), 256, 0, stream>>>(
        Wv + (long)l * 16 * 65536, wqkv_h + 2097152, wqkv_l + 2097152, 64, 1024, 65536, 65536);
    transpose_split<<<dim3(32, 32, 1), 256, 0, stream>>>(
        Wproj + (long)l * 1048576, wp_h, wp_l, 1024, 1024, 0, 0);
    transpose_split<<<dim3(128, 32, 1), 256, 0, stream>>>(
        W1 + (long)l * 4194304, w1t_h, w1t_l, 4096, 1024, 0, 0);
    transpose_split<<<dim3(32, 128, 1), 256, 0, stream>>>(
        W2 + (long)l * 4194304, w2t_h, w2t_l, 1024, 4096, 0, 0);

    // fused QKV: [BT][3072] = hbuf @ Wqkv^T
    gemm_mfma<<<dim3(24, 32), 256, 0, stream>>>(
        hbuf_h, hbuf_l, wqkv_h, wqkv_l, nullptr, nullptr, qkvb, nullptr, nullptr, 3072, 1024, 0);
    attention_tile_kernel<<<dim3(32, 32), 256, 0, stream>>>(qkvb, ab_h, ab_l);
    // proj + bias + residual (in-place on x)
    gemm_mfma<<<dim3(8, 32), 256, 0, stream>>>(
        ab_h, ab_l, wp_h, wp_l, bproj + l * EE, x, x, nullptr, nullptr, 1024, 1024, 0);
    layernorm_kernel<<<BT, 256, 0, stream>>>(x, ln2_g + l * EE, ln2_b + l * EE, hbuf_h, hbuf_l);
    // MLP
    gemm_mfma<<<dim3(32, 32), 256, 0, stream>>>(
        hbuf_h, hbuf_l, w1t_h, w1t_l, b1 + l * FF, nullptr, nullptr, fb_h, fb_l, 4096, 1024, 1);
    gemm_mfma<<<dim3(8, 32), 256, 0, stream>>>(
        fb_h, fb_l, w2t_h, w2t_l, b2 + l * EE, x, x, nullptr, nullptr, 1024, 4096, 0);
  }

  layernorm_kernel<<<BT, 256, 0, stream>>>(x, lnf_g, lnf_b, hbuf_h, hbuf_l);
  // head in 2 N-chunks (conversion scratch reused; logits overwrite out-scratch)
  for (int chunk = 0; chunk < 2; ++chunk) {
    transpose_split<<<dim3(500, 32, 1), 256, 0, stream>>>(
        Whead + chunk * 16000, wh_h, wh_l, 32000, 1024, 0, 0);
    gemm_mfma<<<dim3(125, 32), 256, 0, stream>>>(
        hbuf_h, hbuf_l, wh_h, wh_l, bhead + chunk * 16000, nullptr,
        out + chunk * 16000, nullptr, nullptr, 32000, 1024, 0);
  }

  loss_row_kernel<<<BT, 256, 0, stream>>>(out, targets, row_loss);
  loss_reduce_kernel<<<1, 256, 0, stream>>>(row_loss, out + (long)out_size - 1);
}

// Round 3
// 4998.030 us; speedup vs baseline: 5.6024x; 1.3913x over previous
//
#include <hip/hip_runtime.h>

// Model dims
#define BB 2
#define TT 2048
#define EE 1024
#define HH 16
#define HDD 64
#define VV 32000
#define LL 4
#define FF 4096
#define BT (BB*TT)   // 4096

#define NEG_INF (-__builtin_inff())

typedef _Float16 f16;
typedef f16 f16x8 __attribute__((ext_vector_type(8)));
typedef f16 f16x4v __attribute__((ext_vector_type(4)));
typedef float f32x4 __attribute__((ext_vector_type(4)));

// ---------------- block reduction helpers (256 threads = 4 waves) ----------------
__device__ inline float blockReduceSum256(float v) {
  #pragma unroll
  for (int off = 32; off > 0; off >>= 1) v += __shfl_xor(v, off, 64);
  __shared__ float t[4];
  __syncthreads();
  if ((threadIdx.x & 63) == 0) t[threadIdx.x >> 6] = v;
  __syncthreads();
  return t[0] + t[1] + t[2] + t[3];
}

__device__ inline float blockReduceMax256(float v) {
  #pragma unroll
  for (int off = 32; off > 0; off >>= 1) v = fmaxf(v, __shfl_xor(v, off, 64));
  __shared__ float t[4];
  __syncthreads();
  if ((threadIdx.x & 63) == 0) t[threadIdx.x >> 6] = v;
  __syncthreads();
  return fmaxf(fmaxf(t[0], t[1]), fmaxf(t[2], t[3]));
}

// ---------------- embedding ----------------
__global__ __launch_bounds__(256) void embed_kernel(
    const int* __restrict__ idx, const float* __restrict__ tok,
    const float* __restrict__ pos, float* __restrict__ x) {
  long i = (long)blockIdx.x * 256 + threadIdx.x;  // over BT*EE
  int e = (int)(i % EE);
  long bt = i / EE;
  int t = (int)(bt % TT);
  x[i] = tok[(long)idx[bt] * EE + e] + pos[(long)t * EE + e];
}

// ---------------- layernorm: writes f16 hi/lo (consumers are all GEMM-A) ----------------
__global__ __launch_bounds__(256) void layernorm_kernel(
    const float* __restrict__ x, const float* __restrict__ g,
    const float* __restrict__ b, f16* __restrict__ oh, f16* __restrict__ ol) {
  int row = blockIdx.x;
  const float* xr = x + (long)row * EE;
  int tid = threadIdx.x;
  float local[4];
  float s = 0.f;
  #pragma unroll
  for (int i = 0; i < 4; ++i) { local[i] = xr[tid + i * 256]; s += local[i]; }
  s = blockReduceSum256(s);
  float mean = s * (1.0f / EE);
  float vs = 0.f;
  #pragma unroll
  for (int i = 0; i < 4; ++i) { float d = local[i] - mean; vs += d * d; }
  vs = blockReduceSum256(vs);
  float rstd = rsqrtf(vs * (1.0f / EE) + 1e-5f);
  #pragma unroll
  for (int i = 0; i < 4; ++i) {
    int c = tid + i * 256;
    float v = (local[i] - mean) * rstd * g[c] + b[c];
    f16 h = (f16)v;
    oh[(long)row * EE + c] = h;
    ol[(long)row * EE + c] = (f16)(v - (float)h);
  }
}

// ---------------- transpose + f32 -> f16 hi/lo split ----------------
// in: [R][ldIn-strided] f32 (32x32 tile at r0,c0); out: oh/ol [Cext][R] f16.
__global__ __launch_bounds__(256) void transpose_split(
    const float* __restrict__ in, f16* __restrict__ oh, f16* __restrict__ ol,
    int ldIn, int R, long sIn, long sOut) {
  int z = blockIdx.z;
  in += (long)z * sIn; oh += (long)z * sOut; ol += (long)z * sOut;
  __shared__ float t[32][33];
  int r0 = blockIdx.y * 32, c0 = blockIdx.x * 32;
  int tid = threadIdx.x;
  int rr = tid >> 3, cc = (tid & 7) * 4;
  float4 v = *(const float4*)&in[(long)(r0 + rr) * ldIn + c0 + cc];
  t[rr][cc] = v.x; t[rr][cc + 1] = v.y; t[rr][cc + 2] = v.z; t[rr][cc + 3] = v.w;
  __syncthreads();
  int c = tid >> 3, rb = (tid & 7) * 4;
  f16x4v hv, lv;
  #pragma unroll
  for (int j = 0; j < 4; ++j) {
    float xv = t[rb + j][c];
    f16 h = (f16)xv;
    hv[j] = h; lv[j] = (f16)(xv - (float)h);
  }
  long o = (long)(c0 + c) * R + r0 + rb;
  *(f16x4v*)&oh[o] = hv;
  *(f16x4v*)&ol[o] = lv;
}

// ---------------- split-f16 MFMA GEMM ----------------
// C[m,n] = sum_k A[m,k]*B[k,n] with A = Ah+Al (f16 pair, [M][K]),
// B = Bh+Bl stored TRANSPOSED ([N][K]). 3-product split: AhBh + AhBl + AlBh.
// 128x128 tile, BK=32, 4 waves each owning a 64x64 quadrant of 16x16x32 MFMAs.
// Staging via global_load_lds width=16: linear LDS destination IS the MFMA
// fragment layout (verified in round 2).
// If vt != nullptr: "QKV mode" — cols [0,2048) (q|k) stored to C with ld 2048,
// cols [2048,3072) (v) stored TRANSPOSED to vt[(n-2048)*BT + m] (f32x4 per frag).
__global__ __launch_bounds__(256, 3) void gemm_mfma(
    const f16* __restrict__ Ah, const f16* __restrict__ Al,
    const f16* __restrict__ Bh, const f16* __restrict__ Bl,
    const float* __restrict__ bias, const float* __restrict__ res,
    float* __restrict__ C, f16* __restrict__ Ch, f16* __restrict__ Cl,
    float* __restrict__ vt, int ldC, int K, int relu) {
  __shared__ f16 sm[16384];  // halves: Ah[0,4096) Al[4096) Bh[8192) Bl[12288)
  int tid = threadIdx.x;
  int m0 = blockIdx.y << 7, n0 = blockIdx.x << 7;
  int mloc = ((tid >> 6) << 4) | (tid & 15);
  int kg8 = ((tid >> 4) & 3) << 3;
  long offA = (long)(m0 + mloc) * K + kg8;
  long offB = (long)(n0 + mloc) * K + kg8;
  long off64 = 64L * K;
  int lane = tid & 63;
  int w = tid >> 6, wm = w >> 1, wn = w & 1;

  f32x4 acc[4][4] = {};
  for (int ks = 0; ks < K; ks += 32) {
    #define GLL16(g, l) __builtin_amdgcn_global_load_lds( \
        (const __attribute__((address_space(1))) void*)(g), \
        (__attribute__((address_space(3))) void*)(l), 16, 0, 0)
    GLL16(Ah + offA + ks,         &sm[tid * 8]);
    GLL16(Ah + offA + off64 + ks, &sm[2048 + tid * 8]);
    GLL16(Al + offA + ks,         &sm[4096 + tid * 8]);
    GLL16(Al + offA + off64 + ks, &sm[6144 + tid * 8]);
    GLL16(Bh + offB + ks,         &sm[8192 + tid * 8]);
    GLL16(Bh + offB + off64 + ks, &sm[10240 + tid * 8]);
    GLL16(Bl + offB + ks,         &sm[12288 + tid * 8]);
    GLL16(Bl + offB + off64 + ks, &sm[14336 + tid * 8]);
    __syncthreads();   // compiler drains vmcnt before s_barrier

    f16x8 ahf[4], alf[4];
    #pragma unroll
    for (int mi = 0; mi < 4; ++mi) {
      int s = wm * 4 + mi;
      ahf[mi] = *(const f16x8*)&sm[(s * 64 + lane) * 8];
      alf[mi] = *(const f16x8*)&sm[4096 + (s * 64 + lane) * 8];
    }
    #pragma unroll
    for (int ni = 0; ni < 4; ++ni) {
      int s = wn * 4 + ni;
      f16x8 bhf = *(const f16x8*)&sm[8192 + (s * 64 + lane) * 8];
      f16x8 blf = *(const f16x8*)&sm[12288 + (s * 64 + lane) * 8];
      #pragma unroll
      for (int mi = 0; mi < 4; ++mi) {
        acc[mi][ni] = __builtin_amdgcn_mfma_f32_16x16x32_f16(ahf[mi], bhf, acc[mi][ni], 0, 0, 0);
        acc[mi][ni] = __builtin_amdgcn_mfma_f32_16x16x32_f16(ahf[mi], blf, acc[mi][ni], 0, 0, 0);
        acc[mi][ni] = __builtin_amdgcn_mfma_f32_16x16x32_f16(alf[mi], bhf, acc[mi][ni], 0, 0, 0);
      }
    }
    __syncthreads();
  }

  // epilogue: lane l, reg r -> row (l>>4)*4+r, col l&15 of each 16x16 fragment
  int r0 = m0 + wm * 64 + ((lane >> 4) << 2);
  int c0 = n0 + wn * 64 + (lane & 15);
  if (vt) {  // QKV mode
    #pragma unroll
    for (int ni = 0; ni < 4; ++ni) {
      int cn = c0 + ni * 16;
      #pragma unroll
      for (int mi = 0; mi < 4; ++mi) {
        int rm = r0 + mi * 16;
        if (cn < 2048) {
          #pragma unroll
          for (int r = 0; r < 4; ++r)
            C[(long)(rm + r) * 2048 + cn] = acc[mi][ni][r];
        } else {
          *(f32x4*)&vt[(long)(cn - 2048) * BT + rm] = acc[mi][ni];
        }
      }
    }
    return;
  }
  #pragma unroll
  for (int ni = 0; ni < 4; ++ni) {
    int cn = c0 + ni * 16;
    float bv = bias ? bias[cn] : 0.f;
    #pragma unroll
    for (int mi = 0; mi < 4; ++mi) {
      int rm = r0 + mi * 16;
      #pragma unroll
      for (int r = 0; r < 4; ++r) {
        float v = acc[mi][ni][r] + bv;
        long o = (long)(rm + r) * ldC + cn;
        if (res) v += res[o];
        if (relu) v = fmaxf(v, 0.f);
        if (C) C[o] = v;
        else { f16 h = (f16)v; Ch[o] = h; Cl[o] = (f16)(v - (float)h); }
      }
    }
  }
}

// ---------------- MFMA flash attention ----------------
// qk: [B][T][2048] f32 (q | k, per head 64); vt: [1024 hd][B*T] f32 (V^T).
// Block: 256 thr = 4 waves; 64-query tile per block; KVBLK=64; f16 in, f32 acc.
// Wave w owns query rows w*16..w*16+15. Fragment conventions = gemm_mfma's
// (verified): A/B lane l <-> row l&15, k (l>>4)*8+j; C/D row (l>>4)*4+r, col l&15.
// LDS tiles row-major 64x64 f16 with XOR swizzle (hw ^= (row&7)<<3) ->
// ds_read_b128 fragment reads are 2-way (free); P strip pitch 72 hw per wave.

__device__ inline f16x8 cvt8(float4 a, float4 b, float s) {
  f16x8 r;
  r[0] = (f16)(a.x * s); r[1] = (f16)(a.y * s);
  r[2] = (f16)(a.z * s); r[3] = (f16)(a.w * s);
  r[4] = (f16)(b.x * s); r[5] = (f16)(b.y * s);
  r[6] = (f16)(b.z * s); r[7] = (f16)(b.w * s);
  return r;
}

__device__ inline void stage64(const float* __restrict__ g, long gstride,
                               f16* __restrict__ buf, int tid) {
  int r = tid >> 2, c0 = (tid & 3) * 16;
  const float* src = g + (long)r * gstride + c0;
  float4 a = *(const float4*)src;
  float4 b = *(const float4*)(src + 4);
  float4 c = *(const float4*)(src + 8);
  float4 d = *(const float4*)(src + 12);
  int base = r * 64 + c0;
  int swz = (r & 7) << 3;
  *(f16x8*)&buf[base ^ swz]       = cvt8(a, b, 1.0f);
  *(f16x8*)&buf[(base + 8) ^ swz] = cvt8(c, d, 1.0f);
}

__device__ inline f16x8 frag_rm(const f16* __restrict__ buf, int lane, int rowBase, int kh) {
  int row = rowBase + (lane & 15);
  int idx = row * 64 + kh * 32 + ((lane >> 4) << 3);
  return *(const f16x8*)&buf[idx ^ ((row & 7) << 3)];
}

__global__ __launch_bounds__(256) void attention_mfma_kernel(
    const float* __restrict__ qk, const float* __restrict__ vt,
    f16* __restrict__ abh, f16* __restrict__ abl) {
  __shared__ f16 sm[12800];  // bufK [0,4096) | bufV [4096,8192) | P [8192,12800)
  int qt = gridDim.x - 1 - blockIdx.x;  // long blocks first
  int bh = blockIdx.y;
  int b = bh >> 4, hh = bh & 15;
  int tid = threadIdx.x;
  int lane = tid & 63, w = tid >> 6;
  int g = lane >> 4, t15 = lane & 15;

  const float* qb = qk + ((long)b * TT + (long)qt * 64) * 2048 + hh * 64;
  const float* kb = qk + (long)b * TT * 2048 + 1024 + hh * 64;
  const float* vb = vt + (long)hh * 64 * BT + (long)b * TT;

  // Q fragments direct to regs (rows w*16 + t15), scale 1/8 folded in (exact pow2)
  f16x8 aq[2];
  {
    const float* qr = qb + (long)(w * 16 + t15) * 2048;
    #pragma unroll
    for (int kh = 0; kh < 2; ++kh) {
      const float* p = qr + kh * 32 + g * 8;
      float4 x0 = *(const float4*)p;
      float4 x1 = *(const float4*)(p + 4);
      aq[kh] = cvt8(x0, x1, 0.125f);
    }
  }

  f16* bufK = sm;
  f16* bufV = sm + 4096;
  f16* pw   = sm + 8192 + w * 1152;  // 16 rows x pitch 72 hw, wave-private

  f32x4 o4[4] = {};
  float mrow[4], lrow[4] = {};
  #pragma unroll
  for (int i = 0; i < 4; ++i) mrow[i] = NEG_INF;

  for (int kt = 0; kt <= qt; ++kt) {
    __syncthreads();  // all waves done reading bufK/bufV from prev iter
    stage64(kb + (long)kt * 64 * 2048, 2048, bufK, tid);
    stage64(vb + kt * 64, BT, bufV, tid);
    __syncthreads();

    // S = (Q/8) K^T : 8 MFMAs
    f32x4 s4[4] = {};
    #pragma unroll
    for (int sub = 0; sub < 4; ++sub) {
      #pragma unroll
      for (int kh = 0; kh < 2; ++kh) {
        f16x8 bk = frag_rm(bufK, lane, sub * 16, kh);
        s4[sub] = __builtin_amdgcn_mfma_f32_16x16x32_f16(aq[kh], bk, s4[sub], 0, 0, 0);
      }
    }
    if (kt == qt) {  // causal mask, diagonal tile only
      #pragma unroll
      for (int sub = 0; sub < 4; ++sub)
        #pragma unroll
        for (int r = 0; r < 4; ++r)
          if (sub * 16 + t15 > w * 16 + g * 4 + r) s4[sub][r] = NEG_INF;
    }

    // online softmax; row q = w*16 + g*4 + r spans the 16 lanes sharing g
    float cmax[4], csum[4], alpha[4];
    #pragma unroll
    for (int r = 0; r < 4; ++r)
      cmax[r] = fmaxf(fmaxf(s4[0][r], s4[1][r]), fmaxf(s4[2][r], s4[3][r]));
    #pragma unroll
    for (int off = 1; off < 16; off <<= 1)
      #pragma unroll
      for (int r = 0; r < 4; ++r)
        cmax[r] = fmaxf(cmax[r], __shfl_xor(cmax[r], off, 64));
    #pragma unroll
    for (int r = 0; r < 4; ++r) {
      float mn = fmaxf(mrow[r], cmax[r]);
      alpha[r] = __expf(mrow[r] - mn);  // first tile: exp(-inf) = 0
      mrow[r] = mn;
      csum[r] = 0.f;
    }
    f16 pfrag[4][4];
    #pragma unroll
    for (int sub = 0; sub < 4; ++sub)
      #pragma unroll
      for (int r = 0; r < 4; ++r) {
        float p = __expf(s4[sub][r] - mrow[r]);  // masked -> 0
        csum[r] += p;
        pfrag[sub][r] = (f16)p;
      }
    #pragma unroll
    for (int off = 1; off < 16; off <<= 1)
      #pragma unroll
      for (int r = 0; r < 4; ++r)
        csum[r] += __shfl_xor(csum[r], off, 64);
    #pragma unroll
    for (int r = 0; r < 4; ++r) lrow[r] = lrow[r] * alpha[r] + csum[r];
    #pragma unroll
    for (int sub = 0; sub < 4; ++sub)
      #pragma unroll
      for (int r = 0; r < 4; ++r)
        o4[sub][r] *= alpha[r];

    // P -> wave-private LDS strip (C-layout out, A-layout back in)
    #pragma unroll
    for (int sub = 0; sub < 4; ++sub)
      #pragma unroll
      for (int r = 0; r < 4; ++r)
        pw[(g * 4 + r) * 72 + sub * 16 + t15] = pfrag[sub][r];

    f16x8 pa[2];
    #pragma unroll
    for (int kh = 0; kh < 2; ++kh)
      pa[kh] = *(const f16x8*)&pw[t15 * 72 + kh * 32 + g * 8];

    // O += P V : 8 MFMAs (B-frags from V^T tile)
    #pragma unroll
    for (int sub = 0; sub < 4; ++sub) {
      #pragma unroll
      for (int kh = 0; kh < 2; ++kh) {
        f16x8 bv = frag_rm(bufV, lane, sub * 16, kh);
        o4[sub] = __builtin_amdgcn_mfma_f32_16x16x32_f16(pa[kh], bv, o4[sub], 0, 0, 0);
      }
    }
  }

  // output: rows w*16+g*4+r, cols hh*64 + sub*16 + t15; hi/lo f16
  #pragma unroll
  for (int r = 0; r < 4; ++r) {
    float inv = 1.0f / lrow[r];
    long row = (long)b * TT + (long)qt * 64 + w * 16 + g * 4 + r;
    #pragma unroll
    for (int sub = 0; sub < 4; ++sub) {
      float vv = o4[sub][r] * inv;
      f16 h = (f16)vv;
      long o = row * EE + hh * 64 + sub * 16 + t15;
      abh[o] = h;
      abl[o] = (f16)(vv - (float)h);
    }
  }
}

// ---------------- loss ----------------
__global__ __launch_bounds__(256) void loss_row_kernel(
    const float* __restrict__ logits, const int* __restrict__ targets,
    float* __restrict__ row_loss) {
  int r = blockIdx.x;
  const float* lr = logits + (long)r * VV;
  int tid = threadIdx.x;
  float mx = NEG_INF;
  for (int i = tid; i < VV; i += 256) mx = fmaxf(mx, lr[i]);
  mx = blockReduceMax256(mx);
  float se = 0.f;
  for (int i = tid; i < VV; i += 256) se += expf(lr[i] - mx);
  se = blockReduceSum256(se);
  if (tid == 0) row_loss[r] = -(lr[targets[r]] - mx - logf(se));
}

__global__ __launch_bounds__(256) void loss_reduce_kernel(
    const float* __restrict__ row_loss, float* __restrict__ out_loss) {
  int tid = threadIdx.x;
  float s = 0.f;
  for (int i = tid; i < BT; i += 256) s += row_loss[i];
  s = blockReduceSum256(s);
  if (tid == 0) out_loss[0] = s * (1.0f / BT);
}

// ---------------- launch ----------------
extern "C" void kernel_launch(void* const* d_in, const int* in_sizes, int n_in,
                              void* d_out, int out_size, void* d_ws, size_t ws_size,
                              hipStream_t stream) {
  (void)in_sizes; (void)n_in; (void)ws_size;
  const int*   idx     = (const int*)d_in[0];
  const int*   targets = (const int*)d_in[1];
  const float* tok_emb = (const float*)d_in[2];
  const float* pos_emb = (const float*)d_in[3];
  const float* Wq      = (const float*)d_in[4];
  const float* Wk      = (const float*)d_in[5];
  const float* Wv      = (const float*)d_in[6];
  const float* Wproj   = (const float*)d_in[7];
  const float* bproj   = (const float*)d_in[8];
  const float* ln1_g   = (const float*)d_in[9];
  const float* ln1_b   = (const float*)d_in[10];
  const float* ln2_g   = (const float*)d_in[11];
  const float* ln2_b   = (const float*)d_in[12];
  const float* W1      = (const float*)d_in[13];
  const float* b1      = (const float*)d_in[14];
  const float* W2      = (const float*)d_in[15];
  const float* b2      = (const float*)d_in[16];
  const float* lnf_g   = (const float*)d_in[17];
  const float* lnf_b   = (const float*)d_in[18];
  const float* Whead   = (const float*)d_in[19];
  const float* bhead   = (const float*)d_in[20];
  float* out = (float*)d_out;

  // ---- ws layout (bytes) ----
  char* W = (char*)d_ws;
  float* x      = (float*)(W + 0);            // [BT][E] f32      16,777,216
  f16* hbuf_h   = (f16*)(W + 16777216);       // [BT][E]           8,388,608
  f16* hbuf_l   = (f16*)(W + 25165824);
  f16* wqkv_h   = (f16*)(W + 33554432);       // [3072][1024]      6,291,456
  f16* wqkv_l   = (f16*)(W + 39845888);
  f16* wp_h     = (f16*)(W + 46137344);       // [1024][1024]      2,097,152
  f16* wp_l     = (f16*)(W + 48234496);
  f16* w1t_h    = (f16*)(W + 50331648);       // [4096][1024]      8,388,608
  f16* w1t_l    = (f16*)(W + 58720256);
  f16* w2t_h    = (f16*)(W + 67108864);       // [1024][4096]      8,388,608
  f16* w2t_l    = (f16*)(W + 75497472);
  f16* wh_h     = (f16*)(W + 83886080);       // [16000][1024]    32,768,000
  f16* wh_l     = (f16*)(W + 116654080);
  float* row_loss = (float*)(W + 149422080);  // [BT]

  // ---- scratch inside d_out (dead before head GEMM writes logits) ----
  char* O = (char*)d_out;
  float* qkvb = (float*)(O + 0);              // [BT][2048] f32 (q|k)  33,554,432
  float* vtb  = (float*)(O + 33554432);       // [1024][BT] f32 (V^T)  16,777,216
  f16* ab_h   = (f16*)(O + 50331648);         // [BT][E]                8,388,608
  f16* ab_l   = (f16*)(O + 58720256);
  f16* fb_h   = (f16*)(O + 67108864);         // [BT][4E]              33,554,432
  f16* fb_l   = (f16*)(O + 100663296);        // ends 134,217,728 << 524 MB

  embed_kernel<<<BT * EE / 256, 256, 0, stream>>>(idx, tok_emb, pos_emb, x);

  for (int l = 0; l < LL; ++l) {
    layernorm_kernel<<<BT, 256, 0, stream>>>(x, ln1_g + l * EE, ln1_b + l * EE, hbuf_h, hbuf_l);
    // weight converts (transposed [N][K], hi/lo) into per-layer scratch
    transpose_split<<<dim3(2, 32, 16), 256, 0, stream>>>(
        Wq + (long)l * 16 * 65536, wqkv_h,           wqkv_l,           64, 1024, 65536, 65536);
    transpose_split<<<dim3(2, 32, 16), 256, 0, stream>>>(
        Wk + (long)l * 16 * 65536, wqkv_h + 1048576, wqkv_l + 1048576, 64, 1024, 65536, 65536);
    transpose_split<<<dim3(2, 32, 16), 256, 0, stream>>>(
        Wv + (long)l * 16 * 65536, wqkv_h + 2097152, wqkv_l + 2097152, 64, 1024, 65536, 65536);
    transpose_split<<<dim3(32, 32, 1), 256, 0, stream>>>(
        Wproj + (long)l * 1048576, wp_h, wp_l, 1024, 1024, 0, 0);
    transpose_split<<<dim3(128, 32, 1), 256, 0, stream>>>(
        W1 + (long)l * 4194304, w1t_h, w1t_l, 4096, 1024, 0, 0);
    transpose_split<<<dim3(32, 128, 1), 256, 0, stream>>>(
        W2 + (long)l * 4194304, w2t_h, w2t_l, 1024, 4096, 0, 0);

    // fused QKV: q|k -> qkvb [BT][2048], v -> vtb [1024][BT] (transposed epilogue)
    gemm_mfma<<<dim3(24, 32), 256, 0, stream>>>(
        hbuf_h, hbuf_l, wqkv_h, wqkv_l, nullptr, nullptr, qkvb, nullptr, nullptr,
        vtb, 2048, 1024, 0);
    attention_mfma_kernel<<<dim3(32, 32), 256, 0, stream>>>(qkvb, vtb, ab_h, ab_l);
    // proj + bias + residual (in-place on x)
    gemm_mfma<<<dim3(8, 32), 256, 0, stream>>>(
        ab_h, ab_l, wp_h, wp_l, bproj + l * EE, x, x, nullptr, nullptr,
        nullptr, 1024, 1024, 0);
    layernorm_kernel<<<BT, 256, 0, stream>>>(x, ln2_g + l * EE, ln2_b + l * EE, hbuf_h, hbuf_l);
    // MLP
    gemm_mfma<<<dim3(32, 32), 256, 0, stream>>>(
        hbuf_h, hbuf_l, w1t_h, w1t_l, b1 + l * FF, nullptr, nullptr, fb_h, fb_l,
        nullptr, 4096, 1024, 1);
    gemm_mfma<<<dim3(8, 32), 256, 0, stream>>>(
        fb_h, fb_l, w2t_h, w2t_l, b2 + l * EE, x, x, nullptr, nullptr,
        nullptr, 1024, 4096, 0);
  }

  layernorm_kernel<<<BT, 256, 0, stream>>>(x, lnf_g, lnf_b, hbuf_h, hbuf_l);
  // head in 2 N-chunks (conversion scratch reused; logits overwrite out-scratch)
  for (int chunk = 0; chunk < 2; ++chunk) {
    transpose_split<<<dim3(500, 32, 1), 256, 0, stream>>>(
        Whead + chunk * 16000, wh_h, wh_l, 32000, 1024, 0, 0);
    gemm_mfma<<<dim3(125, 32), 256, 0, stream>>>(
        hbuf_h, hbuf_l, wh_h, wh_l, bhead + chunk * 16000, nullptr,
        out + chunk * 16000, nullptr, nullptr, nullptr, 32000, 1024, 0);
  }

  loss_row_kernel<<<BT, 256, 0, stream>>>(out, targets, row_loss);
  loss_reduce_kernel<<<1, 256, 0, stream>>>(row_loss, out + (long)out_size - 1);
}